// Round 17
// baseline (1093.928 us; speedup 1.0000x reference)
//
#include <hip/hip_runtime.h>
#include <math.h>

// Problem constants
#define B_    256
#define NPTS  1024
#define T_    50

// ---------------------------------------------------------------------------
// ws layout (bytes):
//   [0,       786432)   wp   f32 [64][3][256][4]  packed W_hh (round-7 layout)
//   [786432,  1310720)  henc u32 [256][512]       (f32-bit maxpool via atomicMax)
// ---------------------------------------------------------------------------

__global__ __launch_bounds__(256) void prep_kernel(
    const float* __restrict__ whh, float* __restrict__ wp,
    unsigned* __restrict__ henc) {
  int idx = blockIdx.x * 256 + threadIdx.x;   // grid 768*256 = 196608
  if (idx < 196608) {
    int c = idx & 3;
    int r = idx >> 2;            // (k4*3+j)*256 + t
    int t2 = r & 255;
    int q = r >> 8;              // k4*3 + j
    int j = q % 3;
    int k4 = q / 3;
    wp[idx] = whh[(j * 256 + t2) * 256 + (k4 * 4 + c)];
  }
  if (idx < 131072) henc[idx] = 0u;           // bits 0 == +0.0f; relu>=0 valid
}

// ---------------------------------------------------------------------------
// Encoder. Round-25 = R16 (strip-mine WIN, -65us: batched ds_reads decouple
// the ds/smem lgkmcnt users; R9 diagnosis, R16 confirmation) with the strip
// deepened 4 -> 8: halves the lgkm drain points again (16 groups/pair) and
// doubles the s_load batch per wait window. +8 named h regs (~100-110 VGPR
// total, under the 128 cap @16 waves). Per-accumulator FMA sequence stays
// exactly ascending-k with identical values -> bit-identical output.
// ---------------------------------------------------------------------------
__global__ __launch_bounds__(1024) void enc_kernel(
    const float* __restrict__ data,
    const float* __restrict__ w1, const float* __restrict__ b1,
    const float* __restrict__ w2, const float* __restrict__ b2,
    const float* __restrict__ w3, const float* __restrict__ b3,
    unsigned* __restrict__ henc) {
  __shared__ float h2t[2][128][66];
  const int t = threadIdx.x;
  const int b = blockIdx.x >> 1;
  const int half = blockIdx.x & 1;
  const int lane = t & 63;
  const int wv = __builtin_amdgcn_readfirstlane(t >> 6);   // wave id 0..15

  float m[32];
#pragma unroll
  for (int o = 0; o < 32; ++o) m[o] = 0.0f;                // relu via max w/ 0
  const float* __restrict__ w3b = w3 + wv * 32;

#pragma unroll 1
  for (int pair = 0; pair < 4; ++pair) {
#pragma unroll
    for (int tt = 0; tt < 2; ++tt) {                       // R4 phase-1 x2
      const int ptg = b * NPTS + half * 512 + (pair * 2 + tt) * 64 + lane;
      const float x0 = data[ptg * 3], x1 = data[ptg * 3 + 1], x2 = data[ptg * 3 + 2];
      float a[8];
#pragma unroll
      for (int c = 0; c < 8; ++c) a[c] = b2[wv * 8 + c];   // s_load
#pragma unroll 4
      for (int j = 0; j < 64; ++j) {                       // w1/b1 uniform
        float hj = fmaf(x0, w1[j], fmaf(x1, w1[64 + j], fmaf(x2, w1[128 + j], b1[j])));
        hj = fmaxf(hj, 0.0f);
        const float* __restrict__ w2r = w2 + j * 128 + wv * 8;  // s_load x8
#pragma unroll
        for (int c = 0; c < 8; ++c) a[c] = fmaf(hj, w2r[c], a[c]);
      }
#pragma unroll
      for (int c = 0; c < 8; ++c) h2t[tt][wv * 8 + c][lane] = fmaxf(a[c], 0.0f);
    }
    __syncthreads();

    float acc0[32], acc1[32];
#pragma unroll
    for (int o = 0; o < 32; ++o) {
      acc0[o] = b3[wv * 32 + o];                           // s_load seed (R4)
      acc1[o] = acc0[o];                                   // same b3 value
    }
#pragma unroll 1
    for (int k0 = 0; k0 < 128; k0 += 8) {
      // batch 16 ds_reads; one lgkm event group ahead of the s_load window
      float h00, h01, h02, h03, h04, h05, h06, h07;
      float h10, h11, h12, h13, h14, h15, h16, h17;
      h00 = h2t[0][k0 + 0][lane]; h10 = h2t[1][k0 + 0][lane];
      h01 = h2t[0][k0 + 1][lane]; h11 = h2t[1][k0 + 1][lane];
      h02 = h2t[0][k0 + 2][lane]; h12 = h2t[1][k0 + 2][lane];
      h03 = h2t[0][k0 + 3][lane]; h13 = h2t[1][k0 + 3][lane];
      h04 = h2t[0][k0 + 4][lane]; h14 = h2t[1][k0 + 4][lane];
      h05 = h2t[0][k0 + 5][lane]; h15 = h2t[1][k0 + 5][lane];
      h06 = h2t[0][k0 + 6][lane]; h16 = h2t[1][k0 + 6][lane];
      h07 = h2t[0][k0 + 7][lane]; h17 = h2t[1][k0 + 7][lane];
      // pure s_load + FMA for 8 k's (ascending k, R11-identical order)
#define ENC_K(KK, H0, H1) {                                                  \
      const float* __restrict__ wr = w3b + (k0 + (KK)) * 512;                \
      _Pragma("unroll")                                                      \
      for (int o = 0; o < 32; ++o) {                                         \
        const float w = wr[o];                                               \
        acc0[o] = fmaf(H0, w, acc0[o]);                                      \
        acc1[o] = fmaf(H1, w, acc1[o]);                                      \
      }                                                                      \
    }
      ENC_K(0, h00, h10)
      ENC_K(1, h01, h11)
      ENC_K(2, h02, h12)
      ENC_K(3, h03, h13)
      ENC_K(4, h04, h14)
      ENC_K(5, h05, h15)
      ENC_K(6, h06, h16)
      ENC_K(7, h07, h17)
#undef ENC_K
    }
#pragma unroll
    for (int o = 0; o < 32; ++o)
      m[o] = fmaxf(fmaxf(m[o], acc0[o]), acc1[o]);         // tile order, exact
    __syncthreads();                                       // h2t reuse guard
  }

#pragma unroll
  for (int off = 32; off > 0; off >>= 1) {
#pragma unroll
    for (int o = 0; o < 32; ++o) m[o] = fmaxf(m[o], __shfl_xor(m[o], off, 64));
  }
  if (lane == 0) {
    unsigned* __restrict__ hr = henc + b * 512 + wv * 32;
#pragma unroll
    for (int o = 0; o < 32; ++o) atomicMax(hr + o, __float_as_uint(m[o]));
  }
}

// ---------------------------------------------------------------------------
// Fast f64 exp (Cody-Waite + degree-13 Taylor, exact 1/k! coeffs, branch-
// free, ~1 ulp for |x| < 700). Perturbs vs libm at ~1e-16 rel -> invisible
// at f32 output rounding (f64-perturbation invariance proven rounds 4-7).
// ---------------------------------------------------------------------------
__device__ __forceinline__ double fexp(double x) {
  const double n = rint(x * 1.44269504088896338700e+00);
  const double r = fma(-n, 1.90821492927058770002e-10,
                       fma(-n, 6.93147180369123816490e-01, x));
  double p = 1.0 / 6227020800.0;                 // 1/13!
  p = fma(p, r, 1.0 / 479001600.0);
  p = fma(p, r, 1.0 / 39916800.0);
  p = fma(p, r, 1.0 / 3628800.0);
  p = fma(p, r, 1.0 / 362880.0);
  p = fma(p, r, 1.0 / 40320.0);
  p = fma(p, r, 1.0 / 5040.0);
  p = fma(p, r, 1.0 / 720.0);
  p = fma(p, r, 1.0 / 120.0);
  p = fma(p, r, 1.0 / 24.0);
  p = fma(p, r, 1.0 / 6.0);
  p = fma(p, r, 0.5);
  p = fma(p, r, 1.0);
  p = fma(p, r, 1.0);
  return ldexp(p, (int)n);
}
__device__ __forceinline__ double fsigm(double x) { return 1.0 / (1.0 + fexp(-x)); }
__device__ __forceinline__ double ftanh(double y) {
  const double e = fexp(-2.0 * y);
  return (1.0 - e) / (1.0 + e);
}

// ---------------------------------------------------------------------------
// GRU rollout, f64 -- R15 version, FROZEN (best gru medians ~638us):
// R4 structure (grid 256, block 576, 2 barriers/step, wave-8 out_mlp) +
// permanent 48KB W_hh LDS slice (first 2 k4 of each half) opening each
// matvec phase. The wp stream is at its structural ceiling (R5/R7/R8
// invariance; R2/R3/R9 register-prefetch spills; R13 DMA regression).
// ---------------------------------------------------------------------------
__global__ __launch_bounds__(576) void gru_kernel(
    const float* __restrict__ henc,     // [256][512] (maxpool bits)
    const float* __restrict__ mw1, const float* __restrict__ mb1,
    const float* __restrict__ mw2, const float* __restrict__ mb2,
    const float* __restrict__ mw3, const float* __restrict__ mb3,
    const float* __restrict__ wih, const float* __restrict__ wp,
    const float* __restrict__ bih, const float* __restrict__ bhh,
    const float* __restrict__ ow1, const float* __restrict__ ob1,
    const float* __restrict__ ow2, const float* __restrict__ ob2,
    const float* __restrict__ ow3, const float* __restrict__ ob3,
    float* __restrict__ dout) {
  __shared__ __align__(16) double h_l[256];     // single sample
  __shared__ double pp[3][256];                 // half1 partials [gate][c]
  __shared__ double o1_l[64];
  __shared__ double o2_l[64];
  __shared__ double gia_l[6];
  __shared__ __align__(16) float wsl[12288];    // W_hh slice: [hh*2+kk][3][1024]
  __shared__ __align__(16) float ow1f[16384];   // phase-0 alias: g1(256d)+g2(128d)
  __shared__ __align__(16) float ow2f[4096];
  __shared__ float ow3f[384];
  __shared__ float wihf[4608];
  __shared__ float bihf[768];

  const int t = threadIdx.x;
  const int s = blockIdx.x;                     // sample

  for (int i = t; i < 4608; i += 576) wihf[i] = wih[i];
  for (int i = t; i < 768; i += 576) bihf[i] = bih[i];

  double* const g1_l = (double*)ow1f;           // 256 doubles (phase 0 only)
  double* const g2_l = (double*)ow1f + 256;     // 128 doubles (phase 0 only)

  // ---- phase 0: gru_h init MLP (512->256->128->256), f64 (round-7 math) --
  if (t < 256) {
    const float* __restrict__ hrow = henc + (s << 9);
    double a = (double)mb1[t];
#pragma unroll 4
    for (int k = 0; k < 512; ++k)
      a = fma((double)hrow[k], (double)mw1[k * 256 + t], a);
    g1_l[t] = fmax(a, 0.0);
  }
  __syncthreads();
  if (t < 128) {
    double a = (double)mb2[t];
#pragma unroll 4
    for (int k = 0; k < 256; ++k) a = fma(g1_l[k], (double)mw2[k * 128 + t], a);
    g2_l[t] = fmax(a, 0.0);
  }
  __syncthreads();
  if (t < 256) {
    double a = (double)mb3[t];
#pragma unroll 4
    for (int k = 0; k < 128; ++k) a = fma(g2_l[k], (double)mw3[k * 256 + t], a);
    h_l[t] = a;
  }
  if (t < 6) gia_l[t] = 0.0;
  __syncthreads();                    // phase-0 reads of g1/g2 complete

  // ---- stage out_mlp f32 weights + W_hh LDS slice ----
  for (int i = t; i < 16384; i += 576) ow1f[i] = ow1[i];
  for (int i = t; i < 4096; i += 576) ow2f[i] = ow2[i];
  if (t < 384) ow3f[t] = ow3[t];
  // slice chunk ch = hh*2+kk holds wp k4 = hh*32+kk, verbatim copy
  for (int i = t; i < 12288; i += 576) {
    const int ch = i / 3072, off = i - ch * 3072;
    wsl[i] = wp[((ch >> 1) * 32 + (ch & 1)) * 3072 + off];
  }
  __syncthreads();                    // slice + staged weights visible

  // ---- thread constants ----
  const int c = t & 255;
  const int hh = (t >> 8) & 1;                 // k-half (t<512)
  const int khome = hh << 5;                   // k4 range [khome, khome+32)
  const double br = (t < 512 && hh == 0) ? (double)bhh[c] : 0.0;
  const double bz = (t < 512 && hh == 0) ? (double)bhh[256 + c] : 0.0;
  const double bn = (t < 512 && hh == 0) ? (double)bhh[512 + c] : 0.0;
  double hreg = (t < 256) ? h_l[c] : 0.0;      // own phase-0 write
  const float* const wpc = wp + c * 4;
  const float* const wslc = wsl + hh * 6144 + c * 4;   // this half's 2 chunks

  // out_mlp constants (wave 8)
  const int ln = t & 63;
  double ob1d = 0.0, ob2d = 0.0, ob3d = 0.0;
  if (t >= 512) {
    ob1d = (double)ob1[ln];
    ob2d = (double)ob2[ln];
    if (ln < 6) ob3d = (double)ob3[ln];
  }

  double ar, az, an;

  // FMA body shared by both sources; order identical to R4's chain:
  // ar: w.x,w.y,w.z,w.w then az x4 then an x4, k4 ascending.
#define MV_BODY(kk, WR, WZ, WN) {                                            \
    const double2 ha = *(const double2*)(h_l + ((khome + (kk)) << 2));       \
    const double2 hb = *(const double2*)(h_l + ((khome + (kk)) << 2) + 2);   \
    ar = fma(ha.x, (double)WR.x, ar); ar = fma(ha.y, (double)WR.y, ar);      \
    ar = fma(hb.x, (double)WR.z, ar); ar = fma(hb.y, (double)WR.w, ar);      \
    az = fma(ha.x, (double)WZ.x, az); az = fma(ha.y, (double)WZ.y, az);      \
    az = fma(hb.x, (double)WZ.z, az); az = fma(hb.y, (double)WZ.w, az);      \
    an = fma(ha.x, (double)WN.x, an); an = fma(ha.y, (double)WN.y, an);      \
    an = fma(hb.x, (double)WN.z, an); an = fma(hb.y, (double)WN.w, an);      \
  }

  // kk = 0,1: LDS-resident slice (ds_read_b128); same values/order as wp
#define MV_K_LDS(kk) {                                                       \
    const float* p_ = wslc + (kk) * 3072;                                    \
    const float4 wr = *(const float4*)(p_);                                  \
    const float4 wz = *(const float4*)(p_ + 1024);                           \
    const float4 wn = *(const float4*)(p_ + 2048);                           \
    MV_BODY(kk, wr, wz, wn)                                                  \
  }

  // kk >= 2: global JIT loads (R4 verbatim)
#define MV_K(kk) {                                                           \
    const float* p_ = wpc + (khome + (kk)) * 3072;                           \
    const float4 wr = *(const float4*)(p_);                                  \
    const float4 wz = *(const float4*)(p_ + 1024);                           \
    const float4 wn = *(const float4*)(p_ + 2048);                           \
    MV_BODY(kk, wr, wz, wn)                                                  \
  }

  // ---- prologue: both halves' partials of comb(h0) ----
  if (t < 512) {
    ar = br; az = bz; an = bn;
    MV_K_LDS(0) MV_K_LDS(1)
#pragma unroll 2
    for (int kk = 2; kk < 32; ++kk) MV_K(kk)
    if (hh) { pp[0][c] = ar; pp[1][c] = az; pp[2][c] = an; }
  }
  __syncthreads();                    // pp visible

#pragma unroll 1
  for (int step = 0; step < T_; ++step) {
    // ---- gates (t<256): comb = own half0 (biased) + half1 from pp ----
    if (t < 256) {
      const double cr = ar + pp[0][c];
      const double cz = az + pp[1][c];
      const double cn = an + pp[2][c];
      double gr = (double)bihf[c], gz = (double)bihf[256 + c],
             gn = (double)bihf[512 + c];
#pragma unroll
      for (int a = 0; a < 6; ++a) {
        const double xa = gia_l[a];
        gr = fma((double)wihf[c * 6 + a], xa, gr);
        gz = fma((double)wihf[(256 + c) * 6 + a], xa, gz);
        gn = fma((double)wihf[(512 + c) * 6 + a], xa, gn);
      }
      const double rv = fsigm(cr + gr);
      const double zv = fsigm(cz + gz);
      const double nv = ftanh(fma(rv, cn, gn));
      hreg = fma(zv, hreg - nv, nv);
      h_l[c] = hreg;
    }
    if (t < 512) { ar = br; az = bz; an = bn; }
    __syncthreads();                  // [A] h published

    if (t < 512) {
      // ---- matvec: LDS slice opens the phase, then the global stream ----
      MV_K_LDS(0) MV_K_LDS(1)
#pragma unroll 2
      for (int kk = 2; kk < 32; ++kk) MV_K(kk)
      if (hh) { pp[0][c] = ar; pp[1][c] = az; pp[2][c] = an; }
    } else {
      // ---- out_mlp, wave-private (wave 8) ----
      double a0 = ob1d, a1 = 0.0;     // (ob1 + asc lo) + (asc hi): proven assoc
#pragma unroll 4
      for (int k = 0; k < 128; ++k) {
        a0 = fma(h_l[k], (double)ow1f[k * 64 + ln], a0);
        a1 = fma(h_l[128 + k], (double)ow1f[(128 + k) * 64 + ln], a1);
      }
      o1_l[ln] = fmax(a0 + a1, 0.0);
      __builtin_amdgcn_wave_barrier();                    // own-wave LDS only
      double b0 = ob2d;
#pragma unroll 4
      for (int k = 0; k < 64; ++k)
        b0 = fma(o1_l[k], (double)ow2f[k * 64 + ln], b0);
      o2_l[ln] = fmax(b0, 0.0);
      __builtin_amdgcn_wave_barrier();
      if (ln < 6) {
        double a = ob3d;
#pragma unroll 4
        for (int k = 0; k < 64; ++k)
          a = fma(o2_l[k], (double)ow3f[k * 6 + ln], a);
        const double gi_new = gia_l[ln] + a;
        gia_l[ln] = gi_new;
        dout[s * 300 + step * 6 + ln] = (float)a;              // dws
        dout[76800 + s * 300 + step * 6 + ln] = (float)gi_new; // ws
      }
    }
    __syncthreads();                  // [B] pp + gia ready for next gates
  }
#undef MV_BODY
#undef MV_K_LDS
#undef MV_K
}

extern "C" void kernel_launch(void* const* d_in, const int* in_sizes, int n_in,
                              void* d_out, int out_size, void* d_ws, size_t ws_size,
                              hipStream_t stream) {
  const float* data = (const float*)d_in[0];
  // d_in[1] = horizon (always 50)
  const float* ew1 = (const float*)d_in[2];
  const float* eb1 = (const float*)d_in[3];
  const float* ew2 = (const float*)d_in[4];
  const float* eb2 = (const float*)d_in[5];
  const float* ew3 = (const float*)d_in[6];
  const float* eb3 = (const float*)d_in[7];
  const float* mw1 = (const float*)d_in[8];
  const float* mb1 = (const float*)d_in[9];
  const float* mw2 = (const float*)d_in[10];
  const float* mb2 = (const float*)d_in[11];
  const float* mw3 = (const float*)d_in[12];
  const float* mb3 = (const float*)d_in[13];
  const float* wih = (const float*)d_in[14];
  const float* whh = (const float*)d_in[15];
  const float* bih = (const float*)d_in[16];
  const float* bhh = (const float*)d_in[17];
  const float* ow1 = (const float*)d_in[18];
  const float* ob1 = (const float*)d_in[19];
  const float* ow2 = (const float*)d_in[20];
  const float* ob2 = (const float*)d_in[21];
  const float* ow3 = (const float*)d_in[22];
  const float* ob3 = (const float*)d_in[23];
  float* out = (float*)d_out;

  char* ws = (char*)d_ws;
  float*    wp   = (float*)(ws);                 // 786432 B
  unsigned* henc = (unsigned*)(ws + 786432);     // 524288 B -> end 1310720

  prep_kernel<<<768, 256, 0, stream>>>(whh, wp, henc);
  enc_kernel<<<512, 1024, 0, stream>>>(data, ew1, eb1, ew2, eb2, ew3, eb3, henc);
  gru_kernel<<<256, 576, 0, stream>>>((const float*)henc,
                                      mw1, mb1, mw2, mb2, mw3, mb3,
                                      wih, wp, bih, bhh,
                                      ow1, ob1, ow2, ob2, ow3, ob3,
                                      out);
}

// Round 18
// 1061.398 us; speedup vs baseline: 1.0306x; 1.0306x over previous
//
#include <hip/hip_runtime.h>
#include <math.h>

// Problem constants
#define B_    256
#define NPTS  1024
#define T_    50

// ---------------------------------------------------------------------------
// ws layout (bytes):
//   [0,       786432)   wp   f32 [64][3][256][4]  packed W_hh (round-7 layout)
//   [786432,  1310720)  henc u32 [256][512]       (f32-bit maxpool via atomicMax)
// ---------------------------------------------------------------------------

__global__ __launch_bounds__(256) void prep_kernel(
    const float* __restrict__ whh, float* __restrict__ wp,
    unsigned* __restrict__ henc) {
  int idx = blockIdx.x * 256 + threadIdx.x;   // grid 768*256 = 196608
  if (idx < 196608) {
    int c = idx & 3;
    int r = idx >> 2;            // (k4*3+j)*256 + t
    int t2 = r & 255;
    int q = r >> 8;              // k4*3 + j
    int j = q % 3;
    int k4 = q / 3;
    wp[idx] = whh[(j * 256 + t2) * 256 + (k4 * 4 + c)];
  }
  if (idx < 131072) henc[idx] = 0u;           // bits 0 == +0.0f; relu>=0 valid
}

// ---------------------------------------------------------------------------
// Encoder. R16 WINNER VERBATIM (1068us total): R11 2-tile structure +
// phase-2 k strip-mining at depth 4 -- batch the 8 ds_reads (hk0/hk1 x4)
// before the weight loop, one lgkm drain, then 4 k's of pure s_load+FMA.
// Mechanism (R9 diagnosis, R16 confirmation): SMEM returns out-of-order, so
// a wait covering a ds_read forces lgkmcnt(0), draining ALL outstanding
// s_loads and re-exposing their miss latency when ds and smem interleave.
// Depth 8 (R17) regressed (register pressure / batch length past the sweet
// spot); depth 4 is the optimum. FMA order per accumulator unchanged
// (ascending k, same values) -> bit-identical output.
// ---------------------------------------------------------------------------
__global__ __launch_bounds__(1024) void enc_kernel(
    const float* __restrict__ data,
    const float* __restrict__ w1, const float* __restrict__ b1,
    const float* __restrict__ w2, const float* __restrict__ b2,
    const float* __restrict__ w3, const float* __restrict__ b3,
    unsigned* __restrict__ henc) {
  __shared__ float h2t[2][128][66];
  const int t = threadIdx.x;
  const int b = blockIdx.x >> 1;
  const int half = blockIdx.x & 1;
  const int lane = t & 63;
  const int wv = __builtin_amdgcn_readfirstlane(t >> 6);   // wave id 0..15

  float m[32];
#pragma unroll
  for (int o = 0; o < 32; ++o) m[o] = 0.0f;                // relu via max w/ 0
  const float* __restrict__ w3b = w3 + wv * 32;

#pragma unroll 1
  for (int pair = 0; pair < 4; ++pair) {
#pragma unroll
    for (int tt = 0; tt < 2; ++tt) {                       // R4 phase-1 x2
      const int ptg = b * NPTS + half * 512 + (pair * 2 + tt) * 64 + lane;
      const float x0 = data[ptg * 3], x1 = data[ptg * 3 + 1], x2 = data[ptg * 3 + 2];
      float a[8];
#pragma unroll
      for (int c = 0; c < 8; ++c) a[c] = b2[wv * 8 + c];   // s_load
#pragma unroll 4
      for (int j = 0; j < 64; ++j) {                       // w1/b1 uniform
        float hj = fmaf(x0, w1[j], fmaf(x1, w1[64 + j], fmaf(x2, w1[128 + j], b1[j])));
        hj = fmaxf(hj, 0.0f);
        const float* __restrict__ w2r = w2 + j * 128 + wv * 8;  // s_load x8
#pragma unroll
        for (int c = 0; c < 8; ++c) a[c] = fmaf(hj, w2r[c], a[c]);
      }
#pragma unroll
      for (int c = 0; c < 8; ++c) h2t[tt][wv * 8 + c][lane] = fmaxf(a[c], 0.0f);
    }
    __syncthreads();

    float acc0[32], acc1[32];
#pragma unroll
    for (int o = 0; o < 32; ++o) {
      acc0[o] = b3[wv * 32 + o];                           // s_load seed (R4)
      acc1[o] = acc0[o];                                   // same b3 value
    }
#pragma unroll 1
    for (int k0 = 0; k0 < 128; k0 += 4) {
      // batch ds_reads; one lgkm event group ahead of the s_load window
      float h00, h01, h02, h03, h10, h11, h12, h13;
      h00 = h2t[0][k0 + 0][lane]; h10 = h2t[1][k0 + 0][lane];
      h01 = h2t[0][k0 + 1][lane]; h11 = h2t[1][k0 + 1][lane];
      h02 = h2t[0][k0 + 2][lane]; h12 = h2t[1][k0 + 2][lane];
      h03 = h2t[0][k0 + 3][lane]; h13 = h2t[1][k0 + 3][lane];
      // pure s_load + FMA for 4 k's (ascending k, R11-identical order)
#define ENC_K(KK, H0, H1) {                                                  \
      const float* __restrict__ wr = w3b + (k0 + (KK)) * 512;                \
      _Pragma("unroll")                                                      \
      for (int o = 0; o < 32; ++o) {                                         \
        const float w = wr[o];                                               \
        acc0[o] = fmaf(H0, w, acc0[o]);                                      \
        acc1[o] = fmaf(H1, w, acc1[o]);                                      \
      }                                                                      \
    }
      ENC_K(0, h00, h10)
      ENC_K(1, h01, h11)
      ENC_K(2, h02, h12)
      ENC_K(3, h03, h13)
#undef ENC_K
    }
#pragma unroll
    for (int o = 0; o < 32; ++o)
      m[o] = fmaxf(fmaxf(m[o], acc0[o]), acc1[o]);         // tile order, exact
    __syncthreads();                                       // h2t reuse guard
  }

#pragma unroll
  for (int off = 32; off > 0; off >>= 1) {
#pragma unroll
    for (int o = 0; o < 32; ++o) m[o] = fmaxf(m[o], __shfl_xor(m[o], off, 64));
  }
  if (lane == 0) {
    unsigned* __restrict__ hr = henc + b * 512 + wv * 32;
#pragma unroll
    for (int o = 0; o < 32; ++o) atomicMax(hr + o, __float_as_uint(m[o]));
  }
}

// ---------------------------------------------------------------------------
// Fast f64 exp (Cody-Waite + degree-13 Taylor, exact 1/k! coeffs, branch-
// free, ~1 ulp for |x| < 700). Perturbs vs libm at ~1e-16 rel -> invisible
// at f32 output rounding (f64-perturbation invariance proven rounds 4-7).
// ---------------------------------------------------------------------------
__device__ __forceinline__ double fexp(double x) {
  const double n = rint(x * 1.44269504088896338700e+00);
  const double r = fma(-n, 1.90821492927058770002e-10,
                       fma(-n, 6.93147180369123816490e-01, x));
  double p = 1.0 / 6227020800.0;                 // 1/13!
  p = fma(p, r, 1.0 / 479001600.0);
  p = fma(p, r, 1.0 / 39916800.0);
  p = fma(p, r, 1.0 / 3628800.0);
  p = fma(p, r, 1.0 / 362880.0);
  p = fma(p, r, 1.0 / 40320.0);
  p = fma(p, r, 1.0 / 5040.0);
  p = fma(p, r, 1.0 / 720.0);
  p = fma(p, r, 1.0 / 120.0);
  p = fma(p, r, 1.0 / 24.0);
  p = fma(p, r, 1.0 / 6.0);
  p = fma(p, r, 0.5);
  p = fma(p, r, 1.0);
  p = fma(p, r, 1.0);
  return ldexp(p, (int)n);
}
__device__ __forceinline__ double fsigm(double x) { return 1.0 / (1.0 + fexp(-x)); }
__device__ __forceinline__ double ftanh(double y) {
  const double e = fexp(-2.0 * y);
  return (1.0 - e) / (1.0 + e);
}

// ---------------------------------------------------------------------------
// GRU rollout, f64 -- R15 version, FROZEN (best gru medians ~638us):
// R4 structure (grid 256, block 576, 2 barriers/step, wave-8 out_mlp) +
// permanent 48KB W_hh LDS slice (first 2 k4 of each half) opening each
// matvec phase. The wp stream is at its structural ceiling (R5/R7/R8
// invariance; R2/R3/R9 register-prefetch spills; R13 DMA regression).
// ---------------------------------------------------------------------------
__global__ __launch_bounds__(576) void gru_kernel(
    const float* __restrict__ henc,     // [256][512] (maxpool bits)
    const float* __restrict__ mw1, const float* __restrict__ mb1,
    const float* __restrict__ mw2, const float* __restrict__ mb2,
    const float* __restrict__ mw3, const float* __restrict__ mb3,
    const float* __restrict__ wih, const float* __restrict__ wp,
    const float* __restrict__ bih, const float* __restrict__ bhh,
    const float* __restrict__ ow1, const float* __restrict__ ob1,
    const float* __restrict__ ow2, const float* __restrict__ ob2,
    const float* __restrict__ ow3, const float* __restrict__ ob3,
    float* __restrict__ dout) {
  __shared__ __align__(16) double h_l[256];     // single sample
  __shared__ double pp[3][256];                 // half1 partials [gate][c]
  __shared__ double o1_l[64];
  __shared__ double o2_l[64];
  __shared__ double gia_l[6];
  __shared__ __align__(16) float wsl[12288];    // W_hh slice: [hh*2+kk][3][1024]
  __shared__ __align__(16) float ow1f[16384];   // phase-0 alias: g1(256d)+g2(128d)
  __shared__ __align__(16) float ow2f[4096];
  __shared__ float ow3f[384];
  __shared__ float wihf[4608];
  __shared__ float bihf[768];

  const int t = threadIdx.x;
  const int s = blockIdx.x;                     // sample

  for (int i = t; i < 4608; i += 576) wihf[i] = wih[i];
  for (int i = t; i < 768; i += 576) bihf[i] = bih[i];

  double* const g1_l = (double*)ow1f;           // 256 doubles (phase 0 only)
  double* const g2_l = (double*)ow1f + 256;     // 128 doubles (phase 0 only)

  // ---- phase 0: gru_h init MLP (512->256->128->256), f64 (round-7 math) --
  if (t < 256) {
    const float* __restrict__ hrow = henc + (s << 9);
    double a = (double)mb1[t];
#pragma unroll 4
    for (int k = 0; k < 512; ++k)
      a = fma((double)hrow[k], (double)mw1[k * 256 + t], a);
    g1_l[t] = fmax(a, 0.0);
  }
  __syncthreads();
  if (t < 128) {
    double a = (double)mb2[t];
#pragma unroll 4
    for (int k = 0; k < 256; ++k) a = fma(g1_l[k], (double)mw2[k * 128 + t], a);
    g2_l[t] = fmax(a, 0.0);
  }
  __syncthreads();
  if (t < 256) {
    double a = (double)mb3[t];
#pragma unroll 4
    for (int k = 0; k < 128; ++k) a = fma(g2_l[k], (double)mw3[k * 256 + t], a);
    h_l[t] = a;
  }
  if (t < 6) gia_l[t] = 0.0;
  __syncthreads();                    // phase-0 reads of g1/g2 complete

  // ---- stage out_mlp f32 weights + W_hh LDS slice ----
  for (int i = t; i < 16384; i += 576) ow1f[i] = ow1[i];
  for (int i = t; i < 4096; i += 576) ow2f[i] = ow2[i];
  if (t < 384) ow3f[t] = ow3[t];
  // slice chunk ch = hh*2+kk holds wp k4 = hh*32+kk, verbatim copy
  for (int i = t; i < 12288; i += 576) {
    const int ch = i / 3072, off = i - ch * 3072;
    wsl[i] = wp[((ch >> 1) * 32 + (ch & 1)) * 3072 + off];
  }
  __syncthreads();                    // slice + staged weights visible

  // ---- thread constants ----
  const int c = t & 255;
  const int hh = (t >> 8) & 1;                 // k-half (t<512)
  const int khome = hh << 5;                   // k4 range [khome, khome+32)
  const double br = (t < 512 && hh == 0) ? (double)bhh[c] : 0.0;
  const double bz = (t < 512 && hh == 0) ? (double)bhh[256 + c] : 0.0;
  const double bn = (t < 512 && hh == 0) ? (double)bhh[512 + c] : 0.0;
  double hreg = (t < 256) ? h_l[c] : 0.0;      // own phase-0 write
  const float* const wpc = wp + c * 4;
  const float* const wslc = wsl + hh * 6144 + c * 4;   // this half's 2 chunks

  // out_mlp constants (wave 8)
  const int ln = t & 63;
  double ob1d = 0.0, ob2d = 0.0, ob3d = 0.0;
  if (t >= 512) {
    ob1d = (double)ob1[ln];
    ob2d = (double)ob2[ln];
    if (ln < 6) ob3d = (double)ob3[ln];
  }

  double ar, az, an;

  // FMA body shared by both sources; order identical to R4's chain:
  // ar: w.x,w.y,w.z,w.w then az x4 then an x4, k4 ascending.
#define MV_BODY(kk, WR, WZ, WN) {                                            \
    const double2 ha = *(const double2*)(h_l + ((khome + (kk)) << 2));       \
    const double2 hb = *(const double2*)(h_l + ((khome + (kk)) << 2) + 2);   \
    ar = fma(ha.x, (double)WR.x, ar); ar = fma(ha.y, (double)WR.y, ar);      \
    ar = fma(hb.x, (double)WR.z, ar); ar = fma(hb.y, (double)WR.w, ar);      \
    az = fma(ha.x, (double)WZ.x, az); az = fma(ha.y, (double)WZ.y, az);      \
    az = fma(hb.x, (double)WZ.z, az); az = fma(hb.y, (double)WZ.w, az);      \
    an = fma(ha.x, (double)WN.x, an); an = fma(ha.y, (double)WN.y, an);      \
    an = fma(hb.x, (double)WN.z, an); an = fma(hb.y, (double)WN.w, an);      \
  }

  // kk = 0,1: LDS-resident slice (ds_read_b128); same values/order as wp
#define MV_K_LDS(kk) {                                                       \
    const float* p_ = wslc + (kk) * 3072;                                    \
    const float4 wr = *(const float4*)(p_);                                  \
    const float4 wz = *(const float4*)(p_ + 1024);                           \
    const float4 wn = *(const float4*)(p_ + 2048);                           \
    MV_BODY(kk, wr, wz, wn)                                                  \
  }

  // kk >= 2: global JIT loads (R4 verbatim)
#define MV_K(kk) {                                                           \
    const float* p_ = wpc + (khome + (kk)) * 3072;                           \
    const float4 wr = *(const float4*)(p_);                                  \
    const float4 wz = *(const float4*)(p_ + 1024);                           \
    const float4 wn = *(const float4*)(p_ + 2048);                           \
    MV_BODY(kk, wr, wz, wn)                                                  \
  }

  // ---- prologue: both halves' partials of comb(h0) ----
  if (t < 512) {
    ar = br; az = bz; an = bn;
    MV_K_LDS(0) MV_K_LDS(1)
#pragma unroll 2
    for (int kk = 2; kk < 32; ++kk) MV_K(kk)
    if (hh) { pp[0][c] = ar; pp[1][c] = az; pp[2][c] = an; }
  }
  __syncthreads();                    // pp visible

#pragma unroll 1
  for (int step = 0; step < T_; ++step) {
    // ---- gates (t<256): comb = own half0 (biased) + half1 from pp ----
    if (t < 256) {
      const double cr = ar + pp[0][c];
      const double cz = az + pp[1][c];
      const double cn = an + pp[2][c];
      double gr = (double)bihf[c], gz = (double)bihf[256 + c],
             gn = (double)bihf[512 + c];
#pragma unroll
      for (int a = 0; a < 6; ++a) {
        const double xa = gia_l[a];
        gr = fma((double)wihf[c * 6 + a], xa, gr);
        gz = fma((double)wihf[(256 + c) * 6 + a], xa, gz);
        gn = fma((double)wihf[(512 + c) * 6 + a], xa, gn);
      }
      const double rv = fsigm(cr + gr);
      const double zv = fsigm(cz + gz);
      const double nv = ftanh(fma(rv, cn, gn));
      hreg = fma(zv, hreg - nv, nv);
      h_l[c] = hreg;
    }
    if (t < 512) { ar = br; az = bz; an = bn; }
    __syncthreads();                  // [A] h published

    if (t < 512) {
      // ---- matvec: LDS slice opens the phase, then the global stream ----
      MV_K_LDS(0) MV_K_LDS(1)
#pragma unroll 2
      for (int kk = 2; kk < 32; ++kk) MV_K(kk)
      if (hh) { pp[0][c] = ar; pp[1][c] = az; pp[2][c] = an; }
    } else {
      // ---- out_mlp, wave-private (wave 8) ----
      double a0 = ob1d, a1 = 0.0;     // (ob1 + asc lo) + (asc hi): proven assoc
#pragma unroll 4
      for (int k = 0; k < 128; ++k) {
        a0 = fma(h_l[k], (double)ow1f[k * 64 + ln], a0);
        a1 = fma(h_l[128 + k], (double)ow1f[(128 + k) * 64 + ln], a1);
      }
      o1_l[ln] = fmax(a0 + a1, 0.0);
      __builtin_amdgcn_wave_barrier();                    // own-wave LDS only
      double b0 = ob2d;
#pragma unroll 4
      for (int k = 0; k < 64; ++k)
        b0 = fma(o1_l[k], (double)ow2f[k * 64 + ln], b0);
      o2_l[ln] = fmax(b0, 0.0);
      __builtin_amdgcn_wave_barrier();
      if (ln < 6) {
        double a = ob3d;
#pragma unroll 4
        for (int k = 0; k < 64; ++k)
          a = fma(o2_l[k], (double)ow3f[k * 6 + ln], a);
        const double gi_new = gia_l[ln] + a;
        gia_l[ln] = gi_new;
        dout[s * 300 + step * 6 + ln] = (float)a;              // dws
        dout[76800 + s * 300 + step * 6 + ln] = (float)gi_new; // ws
      }
    }
    __syncthreads();                  // [B] pp + gia ready for next gates
  }
#undef MV_BODY
#undef MV_K_LDS
#undef MV_K
}

extern "C" void kernel_launch(void* const* d_in, const int* in_sizes, int n_in,
                              void* d_out, int out_size, void* d_ws, size_t ws_size,
                              hipStream_t stream) {
  const float* data = (const float*)d_in[0];
  // d_in[1] = horizon (always 50)
  const float* ew1 = (const float*)d_in[2];
  const float* eb1 = (const float*)d_in[3];
  const float* ew2 = (const float*)d_in[4];
  const float* eb2 = (const float*)d_in[5];
  const float* ew3 = (const float*)d_in[6];
  const float* eb3 = (const float*)d_in[7];
  const float* mw1 = (const float*)d_in[8];
  const float* mb1 = (const float*)d_in[9];
  const float* mw2 = (const float*)d_in[10];
  const float* mb2 = (const float*)d_in[11];
  const float* mw3 = (const float*)d_in[12];
  const float* mb3 = (const float*)d_in[13];
  const float* wih = (const float*)d_in[14];
  const float* whh = (const float*)d_in[15];
  const float* bih = (const float*)d_in[16];
  const float* bhh = (const float*)d_in[17];
  const float* ow1 = (const float*)d_in[18];
  const float* ob1 = (const float*)d_in[19];
  const float* ow2 = (const float*)d_in[20];
  const float* ob2 = (const float*)d_in[21];
  const float* ow3 = (const float*)d_in[22];
  const float* ob3 = (const float*)d_in[23];
  float* out = (float*)d_out;

  char* ws = (char*)d_ws;
  float*    wp   = (float*)(ws);                 // 786432 B
  unsigned* henc = (unsigned*)(ws + 786432);     // 524288 B -> end 1310720

  prep_kernel<<<768, 256, 0, stream>>>(whh, wp, henc);
  enc_kernel<<<512, 1024, 0, stream>>>(data, ew1, eb1, ew2, eb2, ew3, eb3, henc);
  gru_kernel<<<256, 576, 0, stream>>>((const float*)henc,
                                      mw1, mb1, mw2, mb2, mw3, mb3,
                                      wih, wp, bih, bhh,
                                      ow1, ob1, ow2, ob2, ow3, ob3,
                                      out);
}